// Round 1
// baseline (643.386 us; speedup 1.0000x reference)
//
#include <hip/hip_runtime.h>
#include <stdint.h>
#include <math.h>

// B=8, N=2048, H=1024, 2H=2048, M=B*N=16384
#define NB 8
#define NN 2048
#define HH 1024
#define K2 2048
#define MM 16384

typedef unsigned short u16;
typedef __attribute__((ext_vector_type(8))) short short8v;
typedef __attribute__((ext_vector_type(4))) float floatx4;

__device__ __forceinline__ float bf2f(u16 u) { return __uint_as_float(((unsigned)u) << 16); }
__device__ __forceinline__ u16 f2bf(float f) {
  unsigned u = __float_as_uint(f);
  unsigned r = (u + 0x7fffu + ((u >> 16) & 1u)) >> 16;
  return (u16)r;
}

__device__ __forceinline__ void async16(const void* g, void* lds) {
  __builtin_amdgcn_global_load_lds((const __attribute__((address_space(1))) void*)g,
                                   (__attribute__((address_space(3))) void*)lds,
                                   16, 0, 0);
}

// ---- core: 128x128 tile, 4 waves (2x2), BK=32, bf16 MFMA 16x16x32, Bt is [N][K] ----
__device__ __forceinline__ void gemm_core(const u16* __restrict__ A, int lda,
                                          const u16* __restrict__ Bt, int ldb,
                                          int rowA0, int rowB0, int K,
                                          u16* As, u16* Bs, floatx4 acc[4][4]) {
  const int t = threadIdx.x;
  const int w = t >> 6;
  const int l = t & 63;
  const int wr = w >> 1, wc = w & 1;
  const int fr = l & 15;
  const int fk = (l >> 4) << 3;

#pragma unroll
  for (int mi = 0; mi < 4; mi++)
#pragma unroll
    for (int ni = 0; ni < 4; ni++) {
      floatx4 z = {0.f, 0.f, 0.f, 0.f};
      acc[mi][ni] = z;
    }

  const int c0 = t, c1 = t + 256;
  const u16* gA0 = A + (size_t)(rowA0 + (c0 >> 2)) * lda + ((c0 & 3) << 3);
  const u16* gA1 = A + (size_t)(rowA0 + (c1 >> 2)) * lda + ((c1 & 3) << 3);
  const u16* gB0 = Bt + (size_t)(rowB0 + (c0 >> 2)) * ldb + ((c0 & 3) << 3);
  const u16* gB1 = Bt + (size_t)(rowB0 + (c1 >> 2)) * ldb + ((c1 & 3) << 3);
  u16* lA0 = As + (w << 9);
  u16* lA1 = As + 2048 + (w << 9);
  u16* lB0 = Bs + (w << 9);
  u16* lB1 = Bs + 2048 + (w << 9);

  const short* Ass = (const short*)As;
  const short* Bss = (const short*)Bs;

  for (int k0 = 0; k0 < K; k0 += 32) {
    async16(gA0 + k0, lA0);
    async16(gA1 + k0, lA1);
    async16(gB0 + k0, lB0);
    async16(gB1 + k0, lB1);
    __syncthreads();
    short8v af[4], bf[4];
#pragma unroll
    for (int mi = 0; mi < 4; mi++)
      af[mi] = *(const short8v*)&Ass[((wr << 6) + (mi << 4) + fr) * 32 + fk];
#pragma unroll
    for (int ni = 0; ni < 4; ni++)
      bf[ni] = *(const short8v*)&Bss[((wc << 6) + (ni << 4) + fr) * 32 + fk];
#pragma unroll
    for (int mi = 0; mi < 4; mi++)
#pragma unroll
      for (int ni = 0; ni < 4; ni++)
        acc[mi][ni] = __builtin_amdgcn_mfma_f32_16x16x32_bf16(af[mi], bf[ni], acc[mi][ni], 0, 0, 0);
    __syncthreads();
  }
}

// ---- X = bf16(concat(sem, temp)) : [16384][2048] ----
__global__ void __launch_bounds__(256) k_prep_x(const float* __restrict__ sem,
                                                const float* __restrict__ temp,
                                                u16* __restrict__ X) {
  size_t i = (((size_t)blockIdx.x * 256) + threadIdx.x) << 2;
  int row = (int)(i >> 11);
  int col = (int)(i & 2047);
  const float* src = (col < 1024) ? (sem + (size_t)row * 1024 + col)
                                  : (temp + (size_t)row * 1024 + (col - 1024));
  float4 v = *(const float4*)src;
  ushort4 o;
  o.x = f2bf(v.x); o.y = f2bf(v.y); o.z = f2bf(v.z); o.w = f2bf(v.w);
  *(ushort4*)(X + i) = o;
}

// ---- Wt[n][k] = bf16(W[k][n]), W: [2048][1024] f32 ----
__global__ void __launch_bounds__(256) k_transpose_w(const float* __restrict__ W,
                                                     u16* __restrict__ Wt) {
  __shared__ float s[32][33];
  int tile = blockIdx.x;  // 64 k-tiles x 32 n-tiles
  int nt = tile & 31, kt = tile >> 5;
  int tx = threadIdx.x & 31, ty = threadIdx.x >> 5;  // ty: 0..7
  int n0 = nt << 5, k0 = kt << 5;
#pragma unroll
  for (int j = 0; j < 32; j += 8)
    s[ty + j][tx] = W[(size_t)(k0 + ty + j) * 1024 + (n0 + tx)];
  __syncthreads();
#pragma unroll
  for (int j = 0; j < 32; j += 8)
    Wt[(size_t)(n0 + ty + j) * 2048 + (k0 + tx)] = f2bf(s[tx][ty + j]);
}

// ---- projection GEMM: C[M=16384][1024]; vmode=0: row-major bf16; vmode=1: V^T per batch ----
__global__ void __launch_bounds__(256) k_proj(const u16* __restrict__ X, const u16* __restrict__ Wt,
                                              const float* __restrict__ bias,
                                              u16* __restrict__ Out, int vmode) {
  __shared__ __align__(16) u16 As[4096];
  __shared__ __align__(16) u16 Bs[4096];
  int bm = blockIdx.x >> 3, bn = blockIdx.x & 7;
  floatx4 acc[4][4];
  gemm_core(X, K2, Wt, K2, bm * 128, bn * 128, K2, As, Bs, acc);
  const int t = threadIdx.x, w = t >> 6, l = t & 63;
  const int wr = w >> 1, wc = w & 1;
  const int rbase = bm * 128 + wr * 64 + ((l >> 4) << 2);
  const int cbase = bn * 128 + wc * 64 + (l & 15);
#pragma unroll
  for (int mi = 0; mi < 4; mi++)
#pragma unroll
    for (int ni = 0; ni < 4; ni++) {
      int colg = cbase + ni * 16;
      float bv = bias[colg];
#pragma unroll
      for (int i = 0; i < 4; i++) {
        int rowg = rbase + mi * 16 + i;
        u16 ob = f2bf(acc[mi][ni][i] + bv);
        if (vmode) {
          int b = rowg >> 11, n = rowg & 2047;
          Out[((size_t)b * 1024 + colg) * 2048 + n] = ob;
        } else {
          Out[(size_t)rowg * 1024 + colg] = ob;
        }
      }
    }
}

// ---- gate[row] = sigmoid(X[row]·Wg + bg), one wave per row ----
__global__ void __launch_bounds__(256) k_gate(const u16* __restrict__ X, const float* __restrict__ Wg,
                                              const float* __restrict__ bg, float* __restrict__ gate) {
  int row = blockIdx.x * 4 + (threadIdx.x >> 6);
  int l = threadIdx.x & 63;
  const short* xr = (const short*)(X + (size_t)row * 2048);
  float s = 0.f;
#pragma unroll
  for (int i = 0; i < 4; i++) {
    int k = i * 512 + l * 8;
    short8v v = *(const short8v*)&xr[k];
#pragma unroll
    for (int j = 0; j < 8; j++) s += bf2f((u16)v[j]) * Wg[k + j];
  }
#pragma unroll
  for (int off = 32; off > 0; off >>= 1) s += __shfl_xor(s, off);
  if (l == 0) gate[row] = 1.f / (1.f + expf(-(s + bg[0])));
}

// ---- scores: E = exp(Q·K^T/32) bf16, row sums via atomics ----
__global__ void __launch_bounds__(256) k_scores(const u16* __restrict__ Q, const u16* __restrict__ Kb,
                                                u16* __restrict__ E, float* __restrict__ lsum) {
  __shared__ __align__(16) u16 As[4096];
  __shared__ __align__(16) u16 Bs[4096];
  int bid = blockIdx.x;
  int b = bid >> 8, tt = bid & 255;
  int bm = tt >> 4, bn = tt & 15;
  const u16* A = Q + (size_t)b * NN * HH;
  const u16* Bt = Kb + (size_t)b * NN * HH;
  floatx4 acc[4][4];
  gemm_core(A, HH, Bt, HH, bm * 128, bn * 128, HH, As, Bs, acc);
  u16* Eb = E + (size_t)b * NN * NN;
  float* lb = lsum + b * NN;
  const int t = threadIdx.x, w = t >> 6, l = t & 63;
  const int wr = w >> 1, wc = w & 1;
  const int qbase = bm * 128 + wr * 64 + ((l >> 4) << 2);
  const int kbase = bn * 128 + wc * 64 + (l & 15);
#pragma unroll
  for (int mi = 0; mi < 4; mi++)
#pragma unroll
    for (int i = 0; i < 4; i++) {
      int q = qbase + mi * 16 + i;
      float rs = 0.f;
#pragma unroll
      for (int ni = 0; ni < 4; ni++) {
        float e = expf(acc[mi][ni][i] * 0.03125f);
        Eb[(size_t)q * NN + kbase + ni * 16] = f2bf(e);
        rs += e;
      }
      rs += __shfl_xor(rs, 1);
      rs += __shfl_xor(rs, 2);
      rs += __shfl_xor(rs, 4);
      rs += __shfl_xor(rs, 8);
      if ((l & 15) == 0) atomicAdd(&lb[q], rs);
    }
}

// ---- PV: out = (gate/l)·(E @ V) + sem, f32 ----
__global__ void __launch_bounds__(256) k_pv(const u16* __restrict__ E, const u16* __restrict__ Vt,
                                            const float* __restrict__ gate, const float* __restrict__ lsum,
                                            const float* __restrict__ sem, float* __restrict__ out) {
  __shared__ __align__(16) u16 As[4096];
  __shared__ __align__(16) u16 Bs[4096];
  int bid = blockIdx.x;
  int b = bid >> 7, tt = bid & 127;
  int bm = tt >> 3, bn = tt & 7;
  const u16* A = E + (size_t)b * NN * NN;
  const u16* Bt = Vt + (size_t)b * HH * NN;
  floatx4 acc[4][4];
  gemm_core(A, NN, Bt, NN, bm * 128, bn * 128, NN, As, Bs, acc);
  const int t = threadIdx.x, w = t >> 6, l = t & 63;
  const int wr = w >> 1, wc = w & 1;
  const int qbase = bm * 128 + wr * 64 + ((l >> 4) << 2);
  const int hbase = bn * 128 + wc * 64 + (l & 15);
#pragma unroll
  for (int mi = 0; mi < 4; mi++)
#pragma unroll
    for (int i = 0; i < 4; i++) {
      int q = qbase + mi * 16 + i;
      size_t gq = (size_t)b * NN + q;
      float wq = gate[gq] / lsum[gq];
#pragma unroll
      for (int ni = 0; ni < 4; ni++) {
        int h = hbase + ni * 16;
        out[gq * HH + h] = acc[mi][ni][i] * wq + sem[gq * HH + h];
      }
    }
}

// ---- column mean: cm[b][k] = (1/N) * sum_q (gate/l)_q * E[b][q][k] ----
__global__ void __launch_bounds__(256) k_colmean(const u16* __restrict__ E, const float* __restrict__ gate,
                                                 const float* __restrict__ lsum, float* __restrict__ cm) {
  __shared__ float wsh[256];
  int bid = blockIdx.x;           // 8 b x 8 kslice x 8 qchunk
  int b = bid >> 6, rest = bid & 63;
  int ks = rest >> 3, qc = rest & 7;
  int t = threadIdx.x;
  {
    size_t gq = (size_t)b * NN + qc * 256 + t;
    wsh[t] = gate[gq] / lsum[gq];
  }
  __syncthreads();
  int k = ks * 256 + t;
  const u16* Eb = E + ((size_t)b * NN + (size_t)qc * 256) * NN + k;
  float s = 0.f;
  for (int q = 0; q < 256; q++) s += wsh[q] * bf2f(Eb[(size_t)q * NN]);
  atomicAdd(&cm[b * NN + k], s * (1.f / 2048.f));
}

extern "C" void kernel_launch(void* const* d_in, const int* in_sizes, int n_in,
                              void* d_out, int out_size, void* d_ws, size_t ws_size,
                              hipStream_t stream) {
  const float* sem  = (const float*)d_in[0];
  const float* temp = (const float*)d_in[1];
  const float* Wq   = (const float*)d_in[2];
  const float* bq   = (const float*)d_in[3];
  const float* Wk   = (const float*)d_in[4];
  const float* bk   = (const float*)d_in[5];
  const float* Wv   = (const float*)d_in[6];
  const float* bv   = (const float*)d_in[7];
  const float* Wg   = (const float*)d_in[8];
  const float* bg   = (const float*)d_in[9];
  float* out = (float*)d_out;

  char* ws = (char*)d_ws;
  u16* X    = (u16*)ws;                      // 67,108,864 B  (reused as E later)
  u16* E    = X;
  u16* WqT  = (u16*)(ws + 67108864);         // 4 MB each
  u16* WkT  = (u16*)(ws + 71303168);
  u16* WvT  = (u16*)(ws + 75497472);
  u16* Qb   = (u16*)(ws + 79691776);         // 33,554,432 B each
  u16* Kb   = (u16*)(ws + 113246208);
  u16* Vt   = (u16*)(ws + 146800640);
  float* gate = (float*)(ws + 180355072);    // 65,536 B
  float* lsum = (float*)(ws + 180420608);    // 65,536 B

  hipMemsetAsync(lsum, 0, 65536, stream);
  hipMemsetAsync(out + 16777216, 0, 65536, stream);  // colmean region of d_out

  k_prep_x<<<32768, 256, 0, stream>>>(sem, temp, X);
  k_transpose_w<<<2048, 256, 0, stream>>>(Wq, WqT);
  k_transpose_w<<<2048, 256, 0, stream>>>(Wk, WkT);
  k_transpose_w<<<2048, 256, 0, stream>>>(Wv, WvT);
  k_proj<<<1024, 256, 0, stream>>>(X, WqT, bq, Qb, 0);
  k_proj<<<1024, 256, 0, stream>>>(X, WkT, bk, Kb, 0);
  k_proj<<<1024, 256, 0, stream>>>(X, WvT, bv, Vt, 1);
  k_gate<<<4096, 256, 0, stream>>>(X, Wg, bg, gate);
  k_scores<<<2048, 256, 0, stream>>>(Qb, Kb, E, lsum);   // overwrites X with E (X dead now)
  k_pv<<<1024, 256, 0, stream>>>(E, Vt, gate, lsum, sem, out);
  k_colmean<<<512, 256, 0, stream>>>(E, gate, lsum, out + 16777216);
}

// Round 2
// 580.405 us; speedup vs baseline: 1.1085x; 1.1085x over previous
//
#include <hip/hip_runtime.h>
#include <stdint.h>
#include <math.h>

// B=8, N=2048, H=1024, 2H=2048, M=B*N=16384
#define NB 8
#define NN 2048
#define HH 1024
#define K2 2048
#define MM 16384

typedef unsigned short u16;
typedef __attribute__((ext_vector_type(8))) short short8v;
typedef __attribute__((ext_vector_type(4))) float floatx4;

__device__ __forceinline__ float bf2f(u16 u) { return __uint_as_float(((unsigned)u) << 16); }
__device__ __forceinline__ u16 f2bf(float f) {
  unsigned u = __float_as_uint(f);
  unsigned r = (u + 0x7fffu + ((u >> 16) & 1u)) >> 16;
  return (u16)r;
}

__device__ __forceinline__ void async16(const void* g, void* lds) {
  __builtin_amdgcn_global_load_lds((const __attribute__((address_space(1))) void*)g,
                                   (__attribute__((address_space(3))) void*)lds,
                                   16, 0, 0);
}

// bijective XCD swizzle: grids here are all multiples of 8
__device__ __forceinline__ int xcd_swz(int bid, int nblk) {
  return (bid & 7) * (nblk >> 3) + (bid >> 3);
}

// ======================================================================
// 256x256 tile GEMM core. 8 waves (2M x 4N), BK=32, ring-3 LDS double...
// triple-buffer, T2 XOR swizzle on LDS, T4 counted vmcnt (never 0 in
// steady state), T5 setprio around MFMA cluster. Bt is [N][K] (K-major).
// LDS per operand tile: 256 rows x 32 cols bf16 = 16 KB, row stride 64 B,
// physchunk = elemchunk ^ ((row>>1)&3)  (16B chunks, 4 per row).
// Staged with global_load_lds width-16, pre-swizzled global source.
// ======================================================================
__device__ __forceinline__ void gemm256_core(const u16* __restrict__ A, int lda,
                                             const u16* __restrict__ Bt, int ldb,
                                             int rowA0, int rowB0, int K,
                                             u16* sA, u16* sB, floatx4 acc[8][4]) {
  const int t = threadIdx.x;       // 0..511
  const int w = t >> 6, l = t & 63;
  const int wr = w >> 2, wc = w & 3;

#pragma unroll
  for (int mi = 0; mi < 8; mi++)
#pragma unroll
    for (int ni = 0; ni < 4; ni++) { floatx4 z = {0.f,0.f,0.f,0.f}; acc[mi][ni] = z; }

  // ---- staging: thread t covers LDS rows (t>>2) and 128+(t>>2), source chunk pre-swizzled
  const int cS = ((t & 3) ^ ((t >> 3) & 3)) << 3;  // element offset within 32-col K-tile
  const u16* gA0 = A + (size_t)(rowA0 + (t >> 2)) * lda + cS;
  const u16* gA1 = A + (size_t)(rowA0 + 128 + (t >> 2)) * lda + cS;
  const u16* gB0 = Bt + (size_t)(rowB0 + (t >> 2)) * ldb + cS;
  const u16* gB1 = Bt + (size_t)(rowB0 + 128 + (t >> 2)) * ldb + cS;
  // LDS dest: wave-uniform base + lane*16 (global_load_lds requirement)
  char* dA = (char*)sA + (w << 10) + (l << 4);
  char* dB = (char*)sB + (w << 10) + (l << 4);

  // ---- read-side addressing (swizzled)
  const int fr = l & 15;
  const int xr = (fr >> 1) & 3;
  const int ch = ((l >> 4) ^ xr) << 4;             // physical 16B-chunk byte offset
  const int abase = (wr * 128 + fr) * 64 + ch;     // + mi*1024
  const int bbase = (wc * 64 + fr) * 64 + ch;      // + ni*1024

  const int NTt = K >> 5;

#define STG(bi, kt) { const int ko_ = (kt) << 5;                       \
    char* dA_ = dA + (bi) * 16384; char* dB_ = dB + (bi) * 16384;      \
    async16(gA0 + ko_, dA_);        async16(gA1 + ko_, dA_ + 8192);    \
    async16(gB0 + ko_, dB_);        async16(gB1 + ko_, dB_ + 8192); }

  STG(0, 0);
  STG(1, 1);

  int bc = 0, bs = 2;
  for (int tt = 0; tt < NTt; ++tt) {
    // tile tt's 4 loads complete (tile tt+1's 4 may stay in flight)
    if (tt < NTt - 1) { asm volatile("s_waitcnt vmcnt(4)" ::: "memory"); }
    else              { asm volatile("s_waitcnt vmcnt(0)" ::: "memory"); }
    __builtin_amdgcn_s_barrier();   // publish tile tt; seal reads of buffer bs
    if (tt + 2 < NTt) STG(bs, tt + 2);

    const char* a = (const char*)sA + bc * 16384;
    const char* b = (const char*)sB + bc * 16384;
    short8v bfr[4], afr[8];
#pragma unroll
    for (int ni = 0; ni < 4; ni++) bfr[ni] = *(const short8v*)(b + bbase + ni * 1024);
#pragma unroll
    for (int mi = 0; mi < 8; mi++) afr[mi] = *(const short8v*)(a + abase + mi * 1024);
    __builtin_amdgcn_s_setprio(1);
#pragma unroll
    for (int mi = 0; mi < 8; mi++)
#pragma unroll
      for (int ni = 0; ni < 4; ni++)
        acc[mi][ni] = __builtin_amdgcn_mfma_f32_16x16x32_bf16(afr[mi], bfr[ni], acc[mi][ni], 0, 0, 0);
    __builtin_amdgcn_s_setprio(0);
    bc = (bc == 2) ? 0 : bc + 1;
    bs = (bs == 2) ? 0 : bs + 1;
  }
#undef STG
}

// ---- X = bf16(concat(sem, temp)) : [16384][2048] ----
__global__ void __launch_bounds__(256) k_prep_x(const float* __restrict__ sem,
                                                const float* __restrict__ temp,
                                                u16* __restrict__ X) {
  size_t i = (((size_t)blockIdx.x * 256) + threadIdx.x) << 2;
  int row = (int)(i >> 11);
  int col = (int)(i & 2047);
  const float* src = (col < 1024) ? (sem + (size_t)row * 1024 + col)
                                  : (temp + (size_t)row * 1024 + (col - 1024));
  float4 v = *(const float4*)src;
  ushort4 o;
  o.x = f2bf(v.x); o.y = f2bf(v.y); o.z = f2bf(v.z); o.w = f2bf(v.w);
  *(ushort4*)(X + i) = o;
}

// ---- Wt[n][k] = bf16(W[k][n]), W: [2048][1024] f32; dst base pre-offset ----
__global__ void __launch_bounds__(256) k_transpose_w(const float* __restrict__ W,
                                                     u16* __restrict__ Wt) {
  __shared__ float s[32][33];
  int tile = blockIdx.x;  // 64 k-tiles x 32 n-tiles
  int nt = tile & 31, kt = tile >> 5;
  int tx = threadIdx.x & 31, ty = threadIdx.x >> 5;  // ty: 0..7
  int n0 = nt << 5, k0 = kt << 5;
#pragma unroll
  for (int j = 0; j < 32; j += 8)
    s[ty + j][tx] = W[(size_t)(k0 + ty + j) * 1024 + (n0 + tx)];
  __syncthreads();
#pragma unroll
  for (int j = 0; j < 32; j += 8)
    Wt[(size_t)(n0 + ty + j) * 2048 + (k0 + tx)] = f2bf(s[tx][ty + j]);
}

// ---- fused QKV projection: X[16384][2048] @ WqkvT[3072][2048]^T ----
__global__ void __launch_bounds__(512, 2) k_proj_qkv(const u16* __restrict__ X,
                                                     const u16* __restrict__ Wt,
                                                     const float* __restrict__ bq,
                                                     const float* __restrict__ bk,
                                                     const float* __restrict__ bv,
                                                     u16* __restrict__ Qb,
                                                     u16* __restrict__ Kb,
                                                     u16* __restrict__ Vt) {
  __shared__ __align__(16) u16 sA[3 * 8192];
  __shared__ __align__(16) u16 sB[3 * 8192];
  int tile = xcd_swz(blockIdx.x, 768);
  int bm = tile / 12, bn = tile - bm * 12;
  floatx4 acc[8][4];
  gemm256_core(X, K2, Wt, K2, bm * 256, bn * 256, K2, sA, sB, acc);

  const int t = threadIdx.x, w = t >> 6, l = t & 63;
  const int wr = w >> 2, wc = w & 3;
  const int r0 = bm * 256 + wr * 128 + ((l >> 4) << 2);
  const int cg0 = bn * 256 + wc * 64 + (l & 15);
  const int which = bn >> 2;  // 0:Q 1:K 2:V (each spans 4 column tiles)
  const float* bias = which == 0 ? bq : which == 1 ? bk : bv;
#pragma unroll
  for (int ni = 0; ni < 4; ni++) {
    int c1 = (cg0 + ni * 16) & 1023;
    float bvv = bias[c1];
#pragma unroll
    for (int mi = 0; mi < 8; mi++)
#pragma unroll
      for (int i = 0; i < 4; i++) {
        int rg = r0 + mi * 16 + i;
        u16 ob = f2bf(acc[mi][ni][i] + bvv);
        if (which == 0)      Qb[(size_t)rg * 1024 + c1] = ob;
        else if (which == 1) Kb[(size_t)rg * 1024 + c1] = ob;
        else                 Vt[((size_t)(rg >> 11) * 1024 + c1) * 2048 + (rg & 2047)] = ob;
      }
  }
}

// ---- gate[row] = sigmoid(X[row]·Wg + bg), one wave per row ----
__global__ void __launch_bounds__(256) k_gate(const u16* __restrict__ X, const float* __restrict__ Wg,
                                              const float* __restrict__ bg, float* __restrict__ gate) {
  int row = blockIdx.x * 4 + (threadIdx.x >> 6);
  int l = threadIdx.x & 63;
  const short* xr = (const short*)(X + (size_t)row * 2048);
  float s = 0.f;
#pragma unroll
  for (int i = 0; i < 4; i++) {
    int k = i * 512 + l * 8;
    short8v v = *(const short8v*)&xr[k];
#pragma unroll
    for (int j = 0; j < 8; j++) s += bf2f((u16)v[j]) * Wg[k + j];
  }
#pragma unroll
  for (int off = 32; off > 0; off >>= 1) s += __shfl_xor(s, off);
  if (l == 0) gate[row] = 1.f / (1.f + expf(-(s + bg[0])));
}

// ---- scores: E = exp(Q·K^T/32) bf16, row sums via atomics ----
__global__ void __launch_bounds__(512, 2) k_scores(const u16* __restrict__ Q, const u16* __restrict__ Kb,
                                                   u16* __restrict__ E, float* __restrict__ lsum) {
  __shared__ __align__(16) u16 sA[3 * 8192];
  __shared__ __align__(16) u16 sB[3 * 8192];
  int tile = xcd_swz(blockIdx.x, 512);
  int b = tile >> 6, r = tile & 63, bm = r >> 3, bn = r & 7;
  const u16* A = Q + (size_t)b * NN * HH;
  const u16* Bt = Kb + (size_t)b * NN * HH;
  floatx4 acc[8][4];
  gemm256_core(A, HH, Bt, HH, bm * 256, bn * 256, HH, sA, sB, acc);

  u16* Eb = E + (size_t)b * NN * NN;
  float* lb = lsum + b * NN;
  const int t = threadIdx.x, w = t >> 6, l = t & 63;
  const int wr = w >> 2, wc = w & 3;
  const int q0 = bm * 256 + wr * 128 + ((l >> 4) << 2);
  const int k0c = bn * 256 + wc * 64 + (l & 15);
#pragma unroll
  for (int mi = 0; mi < 8; mi++)
#pragma unroll
    for (int i = 0; i < 4; i++) {
      int q = q0 + mi * 16 + i;
      float rs = 0.f;
#pragma unroll
      for (int ni = 0; ni < 4; ni++) {
        float e = expf(acc[mi][ni][i] * 0.03125f);
        Eb[(size_t)q * NN + k0c + ni * 16] = f2bf(e);
        rs += e;
      }
      rs += __shfl_xor(rs, 1);
      rs += __shfl_xor(rs, 2);
      rs += __shfl_xor(rs, 4);
      rs += __shfl_xor(rs, 8);
      if ((l & 15) == 0) atomicAdd(&lb[q], rs);
    }
}

// ---- PV: out = (gate/l)·(E @ V) + sem, f32 ----
__global__ void __launch_bounds__(512, 2) k_pv(const u16* __restrict__ E, const u16* __restrict__ Vt,
                                               const float* __restrict__ gate, const float* __restrict__ lsum,
                                               const float* __restrict__ sem, float* __restrict__ out) {
  __shared__ __align__(16) u16 sA[3 * 8192];
  __shared__ __align__(16) u16 sB[3 * 8192];
  int tile = xcd_swz(blockIdx.x, 256);
  int b = tile >> 5, r = tile & 31, bm = r >> 2, bn = r & 3;
  const u16* A = E + (size_t)b * NN * NN;
  const u16* Bt = Vt + (size_t)b * HH * NN;
  floatx4 acc[8][4];
  gemm256_core(A, NN, Bt, NN, bm * 256, bn * 256, NN, sA, sB, acc);

  const int t = threadIdx.x, w = t >> 6, l = t & 63;
  const int wr = w >> 2, wc = w & 3;
  const int q0 = bm * 256 + wr * 128 + ((l >> 4) << 2);
  const int h0 = bn * 256 + wc * 64 + (l & 15);
#pragma unroll
  for (int mi = 0; mi < 8; mi++)
#pragma unroll
    for (int i = 0; i < 4; i++) {
      int q = q0 + mi * 16 + i;
      size_t gq = (size_t)b * NN + q;
      float wq = gate[gq] / lsum[gq];
#pragma unroll
      for (int ni = 0; ni < 4; ni++) {
        int h = h0 + ni * 16;
        out[gq * HH + h] = acc[mi][ni][i] * wq + sem[gq * HH + h];
      }
    }
}

// ---- column mean: cm[b][k] = (1/N) * sum_q (gate/l)_q * E[b][q][k] ----
__global__ void __launch_bounds__(256) k_colmean(const u16* __restrict__ E, const float* __restrict__ gate,
                                                 const float* __restrict__ lsum, float* __restrict__ cm) {
  __shared__ float wsh[256];
  int bid = blockIdx.x;           // 8 b x 8 kslice x 8 qchunk
  int b = bid >> 6, rest = bid & 63;
  int ks = rest >> 3, qc = rest & 7;
  int t = threadIdx.x;
  {
    size_t gq = (size_t)b * NN + qc * 256 + t;
    wsh[t] = gate[gq] / lsum[gq];
  }
  __syncthreads();
  int k = ks * 256 + t;
  const u16* Eb = E + ((size_t)b * NN + (size_t)qc * 256) * NN + k;
  float s = 0.f;
  for (int q = 0; q < 256; q++) s += wsh[q] * bf2f(Eb[(size_t)q * NN]);
  atomicAdd(&cm[b * NN + k], s * (1.f / 2048.f));
}

extern "C" void kernel_launch(void* const* d_in, const int* in_sizes, int n_in,
                              void* d_out, int out_size, void* d_ws, size_t ws_size,
                              hipStream_t stream) {
  const float* sem  = (const float*)d_in[0];
  const float* temp = (const float*)d_in[1];
  const float* Wq   = (const float*)d_in[2];
  const float* bq   = (const float*)d_in[3];
  const float* Wk   = (const float*)d_in[4];
  const float* bk   = (const float*)d_in[5];
  const float* Wv   = (const float*)d_in[6];
  const float* bv   = (const float*)d_in[7];
  const float* Wg   = (const float*)d_in[8];
  const float* bg   = (const float*)d_in[9];
  float* out = (float*)d_out;

  char* ws = (char*)d_ws;
  u16* X      = (u16*)ws;                      // 67,108,864 B (reused as E later)
  u16* E      = X;
  u16* WqkvT  = (u16*)(ws + 67108864);         // 3072x2048 bf16 = 12,582,912 B
  u16* Qb     = (u16*)(ws + 79691776);         // 33,554,432 B each
  u16* Kb     = (u16*)(ws + 113246208);
  u16* Vt     = (u16*)(ws + 146800640);
  float* gate = (float*)(ws + 180355072);      // 65,536 B
  float* lsum = (float*)(ws + 180420608);      // 65,536 B

  hipMemsetAsync(lsum, 0, 65536, stream);
  hipMemsetAsync(out + 16777216, 0, 65536, stream);  // colmean region of d_out

  k_prep_x<<<32768, 256, 0, stream>>>(sem, temp, X);
  k_transpose_w<<<2048, 256, 0, stream>>>(Wq, WqkvT);
  k_transpose_w<<<2048, 256, 0, stream>>>(Wk, WqkvT + (size_t)1024 * 2048);
  k_transpose_w<<<2048, 256, 0, stream>>>(Wv, WqkvT + (size_t)2048 * 2048);
  k_proj_qkv<<<768, 512, 0, stream>>>(X, WqkvT, bq, bk, bv, Qb, Kb, Vt);
  k_gate<<<4096, 256, 0, stream>>>(X, Wg, bg, gate);
  k_scores<<<512, 512, 0, stream>>>(Qb, Kb, E, lsum);   // overwrites X with E (X dead now)
  k_pv<<<256, 512, 0, stream>>>(E, Vt, gate, lsum, sem, out);
  k_colmean<<<512, 256, 0, stream>>>(E, gate, lsum, out + 16777216);
}

// Round 3
// 580.205 us; speedup vs baseline: 1.1089x; 1.0003x over previous
//
#include <hip/hip_runtime.h>
#include <stdint.h>
#include <math.h>

// B=8, N=2048, H=1024, 2H=2048, M=B*N=16384
#define NB 8
#define NN 2048
#define HH 1024
#define K2 2048
#define MM 16384

typedef unsigned short u16;
typedef __attribute__((ext_vector_type(8))) short short8v;
typedef __attribute__((ext_vector_type(4))) float floatx4;

__device__ __forceinline__ float bf2f(u16 u) { return __uint_as_float(((unsigned)u) << 16); }
__device__ __forceinline__ u16 f2bf(float f) {
  unsigned u = __float_as_uint(f);
  unsigned r = (u + 0x7fffu + ((u >> 16) & 1u)) >> 16;
  return (u16)r;
}

__device__ __forceinline__ void async16(const void* g, void* lds) {
  __builtin_amdgcn_global_load_lds((const __attribute__((address_space(1))) void*)g,
                                   (__attribute__((address_space(3))) void*)lds,
                                   16, 0, 0);
}

// bijective XCD swizzle: grids here are all multiples of 8
__device__ __forceinline__ int xcd_swz(int bid, int nblk) {
  return (bid & 7) * (nblk >> 3) + (bid >> 3);
}

// ======================================================================
// 256x256 tile GEMM core, 8-phase-style schedule (T3+T4), ring-3 LDS.
// 8 waves (2M x 4N), BK=32. Per K-tile: 2 phases, each
//   {ds_read 4-8 b128 ; issue 2 global_load_lds ; barrier ; lgkmcnt(0) ;
//    setprio(1) ; 16 MFMA ; setprio(0) ; barrier}
// Counted vmcnt(4) once per K-tile (end of phase b) -- never 0 in steady
// state. Staging distance = 2 K-tiles (ring-3) => no WAR hazard.
// LDS tile: 256 rows x 32 cols bf16, 64B rows, 16B-chunk XOR swizzle
// phys = chunk ^ ((row>>1)&3); 0 bank conflicts (verified round 2).
// ======================================================================
__device__ __forceinline__ void gemm256_core(const u16* __restrict__ A, int lda,
                                             const u16* __restrict__ Bt, int ldb,
                                             int rowA0, int rowB0, int K,
                                             u16* sA, u16* sB, floatx4 acc[8][4]) {
  const int t = threadIdx.x;       // 0..511
  const int w = t >> 6, l = t & 63;
  const int wr = w >> 2, wc = w & 3;

#pragma unroll
  for (int mi = 0; mi < 8; mi++)
#pragma unroll
    for (int ni = 0; ni < 4; ni++) { floatx4 z = {0.f,0.f,0.f,0.f}; acc[mi][ni] = z; }

  // staging: thread t covers LDS rows (t>>2) and 128+(t>>2); source chunk pre-swizzled
  const int cS = ((t & 3) ^ ((t >> 3) & 3)) << 3;
  const u16* gA0 = A + (size_t)(rowA0 + (t >> 2)) * lda + cS;
  const u16* gA1 = A + (size_t)(rowA0 + 128 + (t >> 2)) * lda + cS;
  const u16* gB0 = Bt + (size_t)(rowB0 + (t >> 2)) * ldb + cS;
  const u16* gB1 = Bt + (size_t)(rowB0 + 128 + (t >> 2)) * ldb + cS;
  char* dA = (char*)sA + (w << 10) + (l << 4);
  char* dB = (char*)sB + (w << 10) + (l << 4);

  // read-side addressing (swizzled)
  const int fr = l & 15;
  const int ch = (((l >> 4) ^ ((fr >> 1) & 3)) << 4);
  const int abase = (wr * 128 + fr) * 64 + ch;     // + mi*1024
  const int bbase = (wc * 64 + fr) * 64 + ch;      // + ni*1024

  const int NT = K >> 5;

#define STGA(bi, kt) { const int ko_ = (kt) << 5; char* d_ = dA + (bi) * 16384; \
    async16(gA0 + ko_, d_); async16(gA1 + ko_, d_ + 8192); }
#define STGB(bi, kt) { const int ko_ = (kt) << 5; char* d_ = dB + (bi) * 16384; \
    async16(gB0 + ko_, d_); async16(gB1 + ko_, d_ + 8192); }

  // prologue: stage tiles 0 and 1; publish tile 0
  STGA(0, 0); STGB(0, 0);
  STGA(1, 1); STGB(1, 1);
  asm volatile("s_waitcnt vmcnt(4)" ::: "memory");
  __builtin_amdgcn_s_barrier();

  int bc = 0, bs = 2;
  for (int tt = 0; tt < NT; ++tt) {
    const char* a = (const char*)sA + bc * 16384;
    const char* b = (const char*)sB + bc * 16384;
    const bool stg = (tt + 2 < NT);

    // ---------------- phase A: B-frags + A-frags 0..3, MFMA mi 0..3 ----------------
    short8v bfr[4], afr[4];
#pragma unroll
    for (int ni = 0; ni < 4; ni++) bfr[ni] = *(const short8v*)(b + bbase + ni * 1024);
#pragma unroll
    for (int mi = 0; mi < 4; mi++) afr[mi] = *(const short8v*)(a + abase + mi * 1024);
    if (stg) STGA(bs, tt + 2);
    __builtin_amdgcn_s_barrier();
    asm volatile("s_waitcnt lgkmcnt(0)" ::: "memory");
    __builtin_amdgcn_s_setprio(1);
#pragma unroll
    for (int mi = 0; mi < 4; mi++)
#pragma unroll
      for (int ni = 0; ni < 4; ni++)
        acc[mi][ni] = __builtin_amdgcn_mfma_f32_16x16x32_bf16(afr[mi], bfr[ni], acc[mi][ni], 0, 0, 0);
    __builtin_amdgcn_s_setprio(0);
    __builtin_amdgcn_s_barrier();

    // ---------------- phase B: A-frags 4..7, MFMA mi 4..7 ----------------
    short8v afr2[4];
#pragma unroll
    for (int mi = 0; mi < 4; mi++) afr2[mi] = *(const short8v*)(a + abase + (4 + mi) * 1024);
    if (stg) STGB(bs, tt + 2);
    __builtin_amdgcn_s_barrier();
    asm volatile("s_waitcnt lgkmcnt(0)" ::: "memory");
    __builtin_amdgcn_s_setprio(1);
#pragma unroll
    for (int mi = 0; mi < 4; mi++)
#pragma unroll
      for (int ni = 0; ni < 4; ni++)
        acc[4 + mi][ni] = __builtin_amdgcn_mfma_f32_16x16x32_bf16(afr2[mi], bfr[ni], acc[4 + mi][ni], 0, 0, 0);
    __builtin_amdgcn_s_setprio(0);
    // publish tile tt+1 (counted: tile tt+2's 4 loads may stay in flight)
    if (tt < NT - 1) {
      if (stg) { asm volatile("s_waitcnt vmcnt(4)" ::: "memory"); }
      else     { asm volatile("s_waitcnt vmcnt(0)" ::: "memory"); }
    }
    __builtin_amdgcn_s_barrier();

    bc = (bc == 2) ? 0 : bc + 1;
    bs = (bs == 2) ? 0 : bs + 1;
  }
#undef STGA
#undef STGB
}

// ---- X = bf16(concat(sem, temp)) : [16384][2048] ----
__global__ void __launch_bounds__(256) k_prep_x(const float* __restrict__ sem,
                                                const float* __restrict__ temp,
                                                u16* __restrict__ X) {
  size_t i = (((size_t)blockIdx.x * 256) + threadIdx.x) << 2;
  int row = (int)(i >> 11);
  int col = (int)(i & 2047);
  const float* src = (col < 1024) ? (sem + (size_t)row * 1024 + col)
                                  : (temp + (size_t)row * 1024 + (col - 1024));
  float4 v = *(const float4*)src;
  ushort4 o;
  o.x = f2bf(v.x); o.y = f2bf(v.y); o.z = f2bf(v.z); o.w = f2bf(v.w);
  *(ushort4*)(X + i) = o;
}

// ---- Wt[n][k] = bf16(W[k][n]), W: [2048][1024] f32 ----
__global__ void __launch_bounds__(256) k_transpose_w(const float* __restrict__ W,
                                                     u16* __restrict__ Wt) {
  __shared__ float s[32][33];
  int tile = blockIdx.x;  // 64 k-tiles x 32 n-tiles
  int nt = tile & 31, kt = tile >> 5;
  int tx = threadIdx.x & 31, ty = threadIdx.x >> 5;  // ty: 0..7
  int n0 = nt << 5, k0 = kt << 5;
#pragma unroll
  for (int j = 0; j < 32; j += 8)
    s[ty + j][tx] = W[(size_t)(k0 + ty + j) * 1024 + (n0 + tx)];
  __syncthreads();
#pragma unroll
  for (int j = 0; j < 32; j += 8)
    Wt[(size_t)(n0 + ty + j) * 2048 + (k0 + tx)] = f2bf(s[tx][ty + j]);
}

// ---- fused QKV projection: X[16384][2048] @ WqkvT[3072][2048]^T ----
__global__ void __launch_bounds__(512, 2) k_proj_qkv(const u16* __restrict__ X,
                                                     const u16* __restrict__ Wt,
                                                     const float* __restrict__ bq,
                                                     const float* __restrict__ bk,
                                                     const float* __restrict__ bv,
                                                     u16* __restrict__ Qb,
                                                     u16* __restrict__ Kb,
                                                     u16* __restrict__ Vt) {
  __shared__ __align__(16) u16 sA[3 * 8192];
  __shared__ __align__(16) u16 sB[3 * 8192];
  int tile = xcd_swz(blockIdx.x, 768);
  int bm = tile / 12, bn = tile - bm * 12;
  floatx4 acc[8][4];
  gemm256_core(X, K2, Wt, K2, bm * 256, bn * 256, K2, sA, sB, acc);

  const int t = threadIdx.x, w = t >> 6, l = t & 63;
  const int wr = w >> 2, wc = w & 3;
  const int r0 = bm * 256 + wr * 128 + ((l >> 4) << 2);
  const int cg0 = bn * 256 + wc * 64 + (l & 15);
  const int which = bn >> 2;  // 0:Q 1:K 2:V (each spans 4 column tiles)
  const float* bias = which == 0 ? bq : which == 1 ? bk : bv;
#pragma unroll
  for (int ni = 0; ni < 4; ni++) {
    int c1 = (cg0 + ni * 16) & 1023;
    float bvv = bias[c1];
#pragma unroll
    for (int mi = 0; mi < 8; mi++)
#pragma unroll
      for (int i = 0; i < 4; i++) {
        int rg = r0 + mi * 16 + i;
        u16 ob = f2bf(acc[mi][ni][i] + bvv);
        if (which == 0)      Qb[(size_t)rg * 1024 + c1] = ob;
        else if (which == 1) Kb[(size_t)rg * 1024 + c1] = ob;
        else                 Vt[((size_t)(rg >> 11) * 1024 + c1) * 2048 + (rg & 2047)] = ob;
      }
  }
}

// ---- gate[row] = sigmoid(X[row]·Wg + bg), one wave per row ----
__global__ void __launch_bounds__(256) k_gate(const u16* __restrict__ X, const float* __restrict__ Wg,
                                              const float* __restrict__ bg, float* __restrict__ gate) {
  int row = blockIdx.x * 4 + (threadIdx.x >> 6);
  int l = threadIdx.x & 63;
  const short* xr = (const short*)(X + (size_t)row * 2048);
  float s = 0.f;
#pragma unroll
  for (int i = 0; i < 4; i++) {
    int k = i * 512 + l * 8;
    short8v v = *(const short8v*)&xr[k];
#pragma unroll
    for (int j = 0; j < 8; j++) s += bf2f((u16)v[j]) * Wg[k + j];
  }
#pragma unroll
  for (int off = 32; off > 0; off >>= 1) s += __shfl_xor(s, off);
  if (l == 0) gate[row] = 1.f / (1.f + expf(-(s + bg[0])));
}

// ---- scores: E = exp(Q·K^T/32) bf16, row sums via atomics ----
__global__ void __launch_bounds__(512, 2) k_scores(const u16* __restrict__ Q, const u16* __restrict__ Kb,
                                                   u16* __restrict__ E, float* __restrict__ lsum) {
  __shared__ __align__(16) u16 sA[3 * 8192];
  __shared__ __align__(16) u16 sB[3 * 8192];
  int tile = xcd_swz(blockIdx.x, 512);
  int b = tile >> 6, r = tile & 63, bm = r >> 3, bn = r & 7;
  const u16* A = Q + (size_t)b * NN * HH;
  const u16* Bt = Kb + (size_t)b * NN * HH;
  floatx4 acc[8][4];
  gemm256_core(A, HH, Bt, HH, bm * 256, bn * 256, HH, sA, sB, acc);

  u16* Eb = E + (size_t)b * NN * NN;
  float* lb = lsum + b * NN;
  const int t = threadIdx.x, w = t >> 6, l = t & 63;
  const int wr = w >> 2, wc = w & 3;
  const int q0 = bm * 256 + wr * 128 + ((l >> 4) << 2);
  const int k0c = bn * 256 + wc * 64 + (l & 15);
#pragma unroll
  for (int mi = 0; mi < 8; mi++)
#pragma unroll
    for (int i = 0; i < 4; i++) {
      int q = q0 + mi * 16 + i;
      float rs = 0.f;
#pragma unroll
      for (int ni = 0; ni < 4; ni++) {
        float e = expf(acc[mi][ni][i] * 0.03125f);
        Eb[(size_t)q * NN + k0c + ni * 16] = f2bf(e);
        rs += e;
      }
      rs += __shfl_xor(rs, 1);
      rs += __shfl_xor(rs, 2);
      rs += __shfl_xor(rs, 4);
      rs += __shfl_xor(rs, 8);
      if ((l & 15) == 0) atomicAdd(&lb[q], rs);
    }
}

// ---- PV: out = (gate/l)·(E @ V) + sem, f32 ----
__global__ void __launch_bounds__(512, 2) k_pv(const u16* __restrict__ E, const u16* __restrict__ Vt,
                                               const float* __restrict__ gate, const float* __restrict__ lsum,
                                               const float* __restrict__ sem, float* __restrict__ out) {
  __shared__ __align__(16) u16 sA[3 * 8192];
  __shared__ __align__(16) u16 sB[3 * 8192];
  int tile = xcd_swz(blockIdx.x, 256);
  int b = tile >> 5, r = tile & 31, bm = r >> 2, bn = r & 3;
  const u16* A = E + (size_t)b * NN * NN;
  const u16* Bt = Vt + (size_t)b * HH * NN;
  floatx4 acc[8][4];
  gemm256_core(A, NN, Bt, NN, bm * 256, bn * 256, NN, sA, sB, acc);

  const int t = threadIdx.x, w = t >> 6, l = t & 63;
  const int wr = w >> 2, wc = w & 3;
  const int q0 = bm * 256 + wr * 128 + ((l >> 4) << 2);
  const int h0 = bn * 256 + wc * 64 + (l & 15);
#pragma unroll
  for (int mi = 0; mi < 8; mi++)
#pragma unroll
    for (int i = 0; i < 4; i++) {
      int q = q0 + mi * 16 + i;
      size_t gq = (size_t)b * NN + q;
      float wq = gate[gq] / lsum[gq];
#pragma unroll
      for (int ni = 0; ni < 4; ni++) {
        int h = h0 + ni * 16;
        out[gq * HH + h] = acc[mi][ni][i] * wq + sem[gq * HH + h];
      }
    }
}

// ---- column mean: cm[b][k] = (1/N) * sum_q (gate/l)_q * E[b][q][k] ----
__global__ void __launch_bounds__(256) k_colmean(const u16* __restrict__ E, const float* __restrict__ gate,
                                                 const float* __restrict__ lsum, float* __restrict__ cm) {
  __shared__ float wsh[256];
  int bid = blockIdx.x;           // 8 b x 8 kslice x 8 qchunk
  int b = bid >> 6, rest = bid & 63;
  int ks = rest >> 3, qc = rest & 7;
  int t = threadIdx.x;
  {
    size_t gq = (size_t)b * NN + qc * 256 + t;
    wsh[t] = gate[gq] / lsum[gq];
  }
  __syncthreads();
  int k = ks * 256 + t;
  const u16* Eb = E + ((size_t)b * NN + (size_t)qc * 256) * NN + k;
  float s = 0.f;
  for (int q = 0; q < 256; q++) s += wsh[q] * bf2f(Eb[(size_t)q * NN]);
  atomicAdd(&cm[b * NN + k], s * (1.f / 2048.f));
}

extern "C" void kernel_launch(void* const* d_in, const int* in_sizes, int n_in,
                              void* d_out, int out_size, void* d_ws, size_t ws_size,
                              hipStream_t stream) {
  const float* sem  = (const float*)d_in[0];
  const float* temp = (const float*)d_in[1];
  const float* Wq   = (const float*)d_in[2];
  const float* bq   = (const float*)d_in[3];
  const float* Wk   = (const float*)d_in[4];
  const float* bk   = (const float*)d_in[5];
  const float* Wv   = (const float*)d_in[6];
  const float* bv   = (const float*)d_in[7];
  const float* Wg   = (const float*)d_in[8];
  const float* bg   = (const float*)d_in[9];
  float* out = (float*)d_out;

  char* ws = (char*)d_ws;
  u16* X      = (u16*)ws;                      // 67,108,864 B (reused as E later)
  u16* E      = X;
  u16* WqkvT  = (u16*)(ws + 67108864);         // 3072x2048 bf16 = 12,582,912 B
  u16* Qb     = (u16*)(ws + 79691776);         // 33,554,432 B each
  u16* Kb     = (u16*)(ws + 113246208);
  u16* Vt     = (u16*)(ws + 146800640);
  float* gate = (float*)(ws + 180355072);      // 65,536 B
  float* lsum = (float*)(ws + 180420608);      // 65,536 B

  hipMemsetAsync(lsum, 0, 65536, stream);
  hipMemsetAsync(out + 16777216, 0, 65536, stream);  // colmean region of d_out

  k_prep_x<<<32768, 256, 0, stream>>>(sem, temp, X);
  k_transpose_w<<<2048, 256, 0, stream>>>(Wq, WqkvT);
  k_transpose_w<<<2048, 256, 0, stream>>>(Wk, WqkvT + (size_t)1024 * 2048);
  k_transpose_w<<<2048, 256, 0, stream>>>(Wv, WqkvT + (size_t)2048 * 2048);
  k_proj_qkv<<<768, 512, 0, stream>>>(X, WqkvT, bq, bk, bv, Qb, Kb, Vt);
  k_gate<<<4096, 256, 0, stream>>>(X, Wg, bg, gate);
  k_scores<<<512, 512, 0, stream>>>(Qb, Kb, E, lsum);   // overwrites X with E (X dead now)
  k_pv<<<256, 512, 0, stream>>>(E, Vt, gate, lsum, sem, out);
  k_colmean<<<512, 256, 0, stream>>>(E, gate, lsum, out + 16777216);
}